// Round 3
// baseline (1797.825 us; speedup 1.0000x reference)
//
#include <hip/hip_runtime.h>
#include <hip/hip_cooperative_groups.h>
#include <cmath>

namespace cg = cooperative_groups;

#define B_   4
#define N_   2466
#define R_   (B_*N_)     // 9864
#define ELLW 96
#define BK   32

// ---------------- all 4 transposes [B,C,P] -> [B,P,C] in one dispatch ----------------
__global__ __launch_bounds__(256) void k_transpose_all(
    const float* __restrict__ c2, const float* __restrict__ c3,
    const float* __restrict__ c4, const float* __restrict__ c5,
    float* __restrict__ t0, float* __restrict__ t1,
    float* __restrict__ t2, float* __restrict__ t3) {
  __shared__ float t[32][33];
  int bid = blockIdx.x;
  const float* in; float* out; int C, P, nx, ny, rem;
  if (bid < 3136)      { in = c2; out = t0; C = 256;  P = 3136; nx = 98; ny = 8;  rem = bid; }
  else if (bid < 4736) { in = c3; out = t1; C = 512;  P = 784;  nx = 25; ny = 16; rem = bid - 3136; }
  else if (bid < 5632) { in = c4; out = t2; C = 1024; P = 196;  nx = 7;  ny = 32; rem = bid - 4736; }
  else                 { in = c5; out = t3; C = 2048; P = 49;   nx = 2;  ny = 64; rem = bid - 5632; }
  int x = rem % nx; int tq = rem / nx; int y = tq % ny; int b = tq / ny;
  int p0 = x * 32, c0 = y * 32;
  int lp = threadIdx.x & 31, lc = threadIdx.x >> 5;
  for (int cc = lc; cc < 32; cc += 8) {
    int c = c0 + cc, p = p0 + lp;
    t[cc][lp] = (c < C && p < P) ? in[((size_t)b*C + c)*P + p] : 0.f;
  }
  __syncthreads();
  for (int pp = lc; pp < 32; pp += 8) {
    int p = p0 + pp, c = c0 + lp;
    if (p < P && c < C) out[((size_t)b*P + p)*C + c] = t[lp][pp];
  }
}

// ---------------- split-K fused vertex-align gather + proj GEMM (unchanged) ----------------
__global__ __launch_bounds__(256) void k_align_gemm(
    const float* __restrict__ tr0, const float* __restrict__ tr1,
    const float* __restrict__ tr2, const float* __restrict__ tr3,
    const float* __restrict__ pos, const float* __restrict__ lin_w,
    float* __restrict__ part, int kchunk) {
  __shared__ float Xs[BK][65];
  __shared__ alignas(16) float Ws[BK][128];
  __shared__ int   sBase[64][4];
  __shared__ float sWgt[64][4];
  int tid = threadIdx.x;
  int m0  = blockIdx.x * 64;
  int s   = blockIdx.y;

  if (tid < 64) {
    int row = m0 + tid;
    const int Sarr[4] = {56, 28, 14, 7};
    const int Carr[4] = {256, 512, 1024, 2048};
    if (row < R_) {
      int b = row / N_;
      float px = pos[row*3+0], py = pos[row*3+1], pz = pos[row*3+2];
      float hh = fminf(fmaxf(248.f*(py/pz)    + 111.5f, 0.f), 223.f);
      float wc = fminf(fmaxf(248.f*(px/(-pz)) + 111.5f, 0.f), 223.f);
      #pragma unroll
      for (int q = 0; q < 4; q++) {
        int S = Sarr[q], C = Carr[q];
        float dv = 224.f / (float)S;
        float x = hh / dv, y = wc / dv;
        int x1 = (int)floorf(x), y1 = (int)floorf(y);
        int x2 = min((int)ceilf(x), S - 1), y2 = min((int)ceilf(y), S - 1);
        sWgt[tid][q]  = (float)((x2 - x1) * (y2 - y1));   // xi==x1,yi==y1 -> only (x1,y1) tap
        sBase[tid][q] = (b * S * S + x1 * S + y1) * C;    // NHWC base; add channel cc
      }
    } else {
      #pragma unroll
      for (int q = 0; q < 4; q++) { sWgt[tid][q] = 0.f; sBase[tid][q] = 0; }
    }
  }
  __syncthreads();

  float acc[8][4];
  #pragma unroll
  for (int r = 0; r < 8; r++)
    #pragma unroll
    for (int c = 0; c < 4; c++) acc[r][c] = 0.f;
  int cx = tid & 31, cy = tid >> 5;

  int kbeg = s * kchunk, kend = kbeg + kchunk;
  for (int k0 = kbeg; k0 < kend; k0 += BK) {
    const float* tr; int off, sI;
    if (k0 < 256)       { tr = tr0; off = 0;    sI = 0; }
    else if (k0 < 768)  { tr = tr1; off = 256;  sI = 1; }
    else if (k0 < 1792) { tr = tr2; off = 768;  sI = 2; }
    else                { tr = tr3; off = 1792; sI = 3; }
    #pragma unroll
    for (int i = 0; i < 8; i++) {
      int e = tid + i * 256;
      int kk = e & 31, m = e >> 5;
      int cc = k0 - off + kk;
      Xs[kk][m] = sWgt[m][sI] * tr[sBase[m][sI] + cc];
    }
    #pragma unroll
    for (int i = 0; i < 4; i++) {
      int slot = tid + i * 256;
      int kk = slot >> 5, c4 = slot & 31;
      *(float4*)&Ws[kk][c4*4] = *(const float4*)&lin_w[(size_t)(k0 + kk)*128 + c4*4];
    }
    __syncthreads();
    #pragma unroll
    for (int kk = 0; kk < BK; kk++) {
      float a[8], bb[4];
      #pragma unroll
      for (int r = 0; r < 8; r++) a[r] = Xs[kk][cy*8 + r];
      float4 bv = *(const float4*)&Ws[kk][cx*4];
      bb[0] = bv.x; bb[1] = bv.y; bb[2] = bv.z; bb[3] = bv.w;
      #pragma unroll
      for (int r = 0; r < 8; r++)
        #pragma unroll
        for (int c = 0; c < 4; c++) acc[r][c] += a[r] * bb[c];
    }
    __syncthreads();
  }

  #pragma unroll
  for (int r = 0; r < 8; r++) {
    int row = m0 + cy*8 + r;
    if (row < R_) {
      float4 v;
      v.x = acc[r][0]; v.y = acc[r][1]; v.z = acc[r][2]; v.w = acc[r][3];
      *(float4*)&part[((size_t)s*R_ + row)*128 + cx*4] = v;
    }
  }
}

// ================= cooperative chain: everything after align =================
struct ChainArgs {
  const float* adj;
  const float* part;
  const float* lin_b;
  const float* vf;
  const float* pos;
  float* xcat;
  int* ell_cols;
  int* ell_cnt;
  const float* w00[3]; const float* w01[3]; const float* pw[3]; const float* pb[3];
  const float* w10[3]; const float* w11[3];
  const float* gf_w0; const float* gf_w1;
  float* sb; float* tb; float* skip; float* hb; float* xc;
  float* out;
  int nsplit;
};

// 32x128-tile GEMM over grid-stride work items (tile x which)
__device__ __forceinline__ void gemm_stage(
    const float* __restrict__ X, int ldx, int K,
    const float* const* Wl, int nwhich, const float* pbias,
    float* const* Ol,
    float (*Xs)[33], float (*Ws)[128]) {
  int tid = threadIdx.x;
  int cx = tid & 31, cy = tid >> 5;
  const int NT = (R_ + 31) / 32;   // 309
  for (int it = blockIdx.x; it < NT * nwhich; it += (int)gridDim.x) {
    int m0 = (it / nwhich) * 32;
    int which = it - (it / nwhich) * nwhich;
    const float* W = Wl[which];
    float* out = Ol[which];
    float acc[4][4];
    #pragma unroll
    for (int r = 0; r < 4; r++)
      #pragma unroll
      for (int c = 0; c < 4; c++) acc[r][c] = 0.f;

    for (int k0 = 0; k0 < K; k0 += BK) {
      int e = tid;
      #pragma unroll
      for (int i = 0; i < 4; i++) {
        int kk = e & 31, m = e >> 5;
        int row = m0 + m, k = k0 + kk;
        Xs[kk][m] = (row < R_ && k < K) ? X[(size_t)row*ldx + k] : 0.f;
        e += 256;
      }
      #pragma unroll
      for (int i = 0; i < 4; i++) {
        int slot = tid + i * 256;
        int kk = slot >> 5, c4 = slot & 31;
        int k = k0 + kk;
        float4 v = make_float4(0.f, 0.f, 0.f, 0.f);
        if (k < K) v = *(const float4*)&W[(size_t)k*128 + c4*4];
        *(float4*)&Ws[kk][c4*4] = v;
      }
      __syncthreads();
      #pragma unroll
      for (int kk = 0; kk < BK; kk++) {
        float av[4];
        #pragma unroll
        for (int r = 0; r < 4; r++) av[r] = Xs[kk][cy*4 + r];
        float4 bv = *(const float4*)&Ws[kk][cx*4];
        float bb[4] = {bv.x, bv.y, bv.z, bv.w};
        #pragma unroll
        for (int r = 0; r < 4; r++)
          #pragma unroll
          for (int c = 0; c < 4; c++) acc[r][c] += av[r] * bb[c];
      }
      __syncthreads();
    }

    #pragma unroll
    for (int r = 0; r < 4; r++) {
      int row = m0 + cy*4 + r;
      if (row < R_) {
        int col = cx * 4;
        float4 v;
        v.x = acc[r][0]; v.y = acc[r][1]; v.z = acc[r][2]; v.w = acc[r][3];
        if (which == 2 && pbias) {
          v.x += pbias[col+0]; v.y += pbias[col+1]; v.z += pbias[col+2]; v.w += pbias[col+3];
        }
        *(float4*)&out[(size_t)row*128 + col] = v;
      }
    }
  }
}

// out = [skip +] relu(s + A@t), 2 rows per 256-thread pass
__device__ __forceinline__ void spmm_stage(
    const float* __restrict__ sbuf, const float* __restrict__ tbuf,
    const int* __restrict__ cols, const int* __restrict__ cnts,
    const float* __restrict__ skipb, float* __restrict__ outb) {
  int tid = threadIdx.x;
  for (int base = blockIdx.x * 2; base < R_; base += (int)gridDim.x * 2) {
    int row = base + (tid >> 7);          // R_ even -> row < R_
    int k = tid & 127;
    int b = row / N_;
    float acc = sbuf[(size_t)row*128 + k];
    int cnt = cnts[row];
    const int* cp = cols + (size_t)row * ELLW;
    size_t tbase = (size_t)b * N_;
    for (int i = 0; i < cnt; i++)
      acc += tbuf[(tbase + cp[i])*128 + k];
    acc = fmaxf(acc, 0.f);
    if (skipb) acc += skipb[(size_t)row*128 + k];
    outb[(size_t)row*128 + k] = acc;
  }
}

__global__ __launch_bounds__(256, 4) void k_chain(ChainArgs a) {
  __shared__ float Xs[BK][33];
  __shared__ alignas(16) float Ws[BK][128];
  cg::grid_group grid = cg::this_grid();
  int tid  = threadIdx.x;
  int wave = tid >> 6, lane = tid & 63;
  int NBX  = (int)gridDim.x;

  // ---- stage 0a: reduce split-K partials + bias -> xcat (proj|vf|pos) ----
  for (int base = blockIdx.x * 2; base < R_; base += NBX * 2) {
    int row = base + (tid >> 7);
    int k = tid & 127;
    float acc = a.lin_b[k];
    for (int s = 0; s < a.nsplit; s++)
      acc += a.part[((size_t)s * R_ + row) * 128 + k];
    a.xcat[(size_t)row * 264 + k]       = acc;
    a.xcat[(size_t)row * 264 + 128 + k] = a.vf[(size_t)row * 128 + k];
    if (k < 3) a.xcat[(size_t)row * 264 + 256 + k] = a.pos[(size_t)row * 3 + k];
  }
  // ---- stage 0b: adjacency -> ELL (one wave per row) ----
  for (int row = blockIdx.x * 4 + wave; row < R_; row += NBX * 4) {
    const float* Ar = a.adj + (size_t)row * N_;
    int* cp = a.ell_cols + (size_t)row * ELLW;
    int cbase = 0;
    for (int j0 = 0; j0 < N_; j0 += 64) {
      int j = j0 + lane;
      bool nz = (j < N_) && (Ar[j] != 0.f);
      unsigned long long mk = __ballot(nz);
      int pos = __popcll(mk & ((1ull << lane) - 1ull));
      if (nz && cbase + pos < ELLW) cp[cbase + pos] = j;
      cbase += __popcll(mk);
    }
    if (lane == 0) a.ell_cnt[row] = (cbase > ELLW) ? ELLW : cbase;
  }
  grid.sync();

  // ---- three residual graph-conv blocks ----
  const float* xin = a.xcat; int ldx = 264, K = 259;
  for (int rb = 0; rb < 3; rb++) {
    {
      const float* Wl[3] = {a.w00[rb], a.w01[rb], a.pw[rb]};
      float* Ol[3] = {a.sb, a.tb, a.skip};
      gemm_stage(xin, ldx, K, Wl, 3, a.pb[rb], Ol, Xs, Ws);
    }
    grid.sync();
    spmm_stage(a.sb, a.tb, a.ell_cols, a.ell_cnt, nullptr, a.hb);
    grid.sync();
    {
      const float* Wl[2] = {a.w10[rb], a.w11[rb]};
      float* Ol[2] = {a.sb, a.tb};
      gemm_stage(a.hb, 128, 128, Wl, 2, nullptr, Ol, Xs, Ws);
    }
    grid.sync();
    spmm_stage(a.sb, a.tb, a.ell_cols, a.ell_cnt, a.skip, a.xc);
    grid.sync();
    xin = a.xc; ldx = 128; K = 128;
  }

  // ---- final graph conv 128->3: gemv (one wave per row) ----
  for (int row = blockIdx.x * 4 + wave; row < R_; row += NBX * 4) {
    float xa = a.xc[(size_t)row * 128 + lane];
    float xb = a.xc[(size_t)row * 128 + 64 + lane];
    #pragma unroll
    for (int c = 0; c < 3; c++) {
      float p = xa * a.gf_w0[lane * 3 + c] + xb * a.gf_w0[(lane + 64) * 3 + c];
      float q = xa * a.gf_w1[lane * 3 + c] + xb * a.gf_w1[(lane + 64) * 3 + c];
      #pragma unroll
      for (int off = 32; off > 0; off >>= 1) {
        p += __shfl_xor(p, off);
        q += __shfl_xor(q, off);
      }
      if (lane == 0) { a.sb[(size_t)row * 128 + c] = p; a.tb[(size_t)row * 128 + c] = q; }
    }
  }
  grid.sync();
  // ---- out = pos + tanh(relu(s + A@t)) ----
  for (int row = blockIdx.x * 4 + wave; row < R_; row += NBX * 4) {
    if (lane < 3) {
      int b = row / N_;
      float acc = a.sb[(size_t)row * 128 + lane];
      int cnt = a.ell_cnt[row];
      const int* cp = a.ell_cols + (size_t)row * ELLW;
      size_t tbase = (size_t)b * N_;
      for (int i = 0; i < cnt; i++)
        acc += a.tb[(tbase + cp[i]) * 128 + lane];
      float v = tanhf(fmaxf(acc, 0.f));
      a.out[(size_t)row * 3 + lane] = a.pos[(size_t)row * 3 + lane] + v;
    }
  }
}

extern "C" void kernel_launch(void* const* d_in, const int* in_sizes, int n_in,
                              void* d_out, int out_size, void* d_ws, size_t ws_size,
                              hipStream_t stream) {
  const float* conv2_3 = (const float*)d_in[0];
  const float* conv3_4 = (const float*)d_in[1];
  const float* conv4_6 = (const float*)d_in[2];
  const float* conv5_3 = (const float*)d_in[3];
  const float* pos     = (const float*)d_in[4];
  const float* vf      = (const float*)d_in[5];
  const float* adj     = (const float*)d_in[6];
  const float* lin_w   = (const float*)d_in[7];
  const float* lin_b   = (const float*)d_in[8];
  const float* gf_w0 = (const float*)d_in[27];
  const float* gf_w1 = (const float*)d_in[28];
  float* out = (float*)d_out;

  // ---- workspace layout (floats) ----
  const size_t TR_TOT = (size_t)4*(256*3136 + 512*784 + 1024*196 + 2048*49);
  const size_t ELL_I  = (size_t)R_ * (ELLW + 1);
  const size_t XCAT_F = (size_t)R_ * 264;

  float* ws  = (float*)d_ws;
  float* tr0 = ws;
  float* tr1 = tr0 + (size_t)4*256*3136;
  float* tr2 = tr1 + (size_t)4*512*784;
  float* tr3 = tr2 + (size_t)4*1024*196;
  int*   ell_cnt  = (int*)(tr3 + (size_t)4*2048*49);
  int*   ell_cols = ell_cnt + R_;
  float* xcat = (float*)(ell_cols + (size_t)R_*ELLW);
  float* buf  = xcat + XCAT_F;          // split-K partials; later sb..xc
  float* sb   = buf;
  float* tb   = sb   + (size_t)R_*128;
  float* skip = tb   + (size_t)R_*128;
  float* hb   = skip + (size_t)R_*128;
  float* xc   = hb   + (size_t)R_*128;

  size_t fixed_f = TR_TOT + ELL_I + XCAT_F;
  size_t need8   = (fixed_f + (size_t)8 * R_ * 128) * sizeof(float);
  int nsplit = (ws_size >= need8) ? 8 : 4;
  int kchunk = 3840 / nsplit;

  // 1) all transposes in one dispatch
  k_transpose_all<<<6144, 256, 0, stream>>>(conv2_3, conv3_4, conv4_6, conv5_3,
                                            tr0, tr1, tr2, tr3);

  // 2) split-K fused align-gather + projection GEMM
  k_align_gemm<<<dim3(155, nsplit), 256, 0, stream>>>(tr0, tr1, tr2, tr3, pos, lin_w, buf, kchunk);

  // 3) everything else: ONE cooperative kernel with grid syncs
  ChainArgs ca;
  ca.adj = adj; ca.part = buf; ca.lin_b = lin_b; ca.vf = vf; ca.pos = pos;
  ca.xcat = xcat; ca.ell_cols = ell_cols; ca.ell_cnt = ell_cnt;
  for (int rb = 0; rb < 3; rb++) {
    ca.pw[rb]  = (const float*)d_in[9  + 6*rb];
    ca.pb[rb]  = (const float*)d_in[10 + 6*rb];
    ca.w00[rb] = (const float*)d_in[11 + 6*rb];
    ca.w01[rb] = (const float*)d_in[12 + 6*rb];
    ca.w10[rb] = (const float*)d_in[13 + 6*rb];
    ca.w11[rb] = (const float*)d_in[14 + 6*rb];
  }
  ca.gf_w0 = gf_w0; ca.gf_w1 = gf_w1;
  ca.sb = sb; ca.tb = tb; ca.skip = skip; ca.hb = hb; ca.xc = xc;
  ca.out = out; ca.nsplit = nsplit;

  int nb = 768;
  int maxPerCU = 0;
  if (hipOccupancyMaxActiveBlocksPerMultiprocessor(&maxPerCU, k_chain, 256, 0) == hipSuccess
      && maxPerCU > 0) {
    int cap = maxPerCU * 256;   // 256 CUs
    if (cap < nb) nb = cap;
  }
  void* kargs[] = {(void*)&ca};
  hipLaunchCooperativeKernel((void*)k_chain, dim3(nb), dim3(256), kargs, 0, stream);
}

// Round 4
// 609.393 us; speedup vs baseline: 2.9502x; 2.9502x over previous
//
#include <hip/hip_runtime.h>
#include <cmath>

#define B_   4
#define N_   2466
#define R_   (B_*N_)     // 9864
#define ELLW 96
#define BK   32

// ---------------- all 4 transposes [B,C,P] -> [B,P,C] in one dispatch ----------------
__global__ __launch_bounds__(256) void k_transpose_all(
    const float* __restrict__ c2, const float* __restrict__ c3,
    const float* __restrict__ c4, const float* __restrict__ c5,
    float* __restrict__ t0, float* __restrict__ t1,
    float* __restrict__ t2, float* __restrict__ t3) {
  __shared__ float t[32][33];
  int bid = blockIdx.x;
  const float* in; float* out; int C, P, nx, ny, rem;
  if (bid < 3136)      { in = c2; out = t0; C = 256;  P = 3136; nx = 98; ny = 8;  rem = bid; }
  else if (bid < 4736) { in = c3; out = t1; C = 512;  P = 784;  nx = 25; ny = 16; rem = bid - 3136; }
  else if (bid < 5632) { in = c4; out = t2; C = 1024; P = 196;  nx = 7;  ny = 32; rem = bid - 4736; }
  else                 { in = c5; out = t3; C = 2048; P = 49;   nx = 2;  ny = 64; rem = bid - 5632; }
  int x = rem % nx; int tq = rem / nx; int y = tq % ny; int b = tq / ny;
  int p0 = x * 32, c0 = y * 32;
  int lp = threadIdx.x & 31, lc = threadIdx.x >> 5;
  for (int cc = lc; cc < 32; cc += 8) {
    int c = c0 + cc, p = p0 + lp;
    t[cc][lp] = (c < C && p < P) ? in[((size_t)b*C + c)*P + p] : 0.f;
  }
  __syncthreads();
  for (int pp = lc; pp < 32; pp += 8) {
    int p = p0 + pp, c = c0 + lp;
    if (p < P && c < C) out[((size_t)b*P + p)*C + c] = t[lp][pp];
  }
}

// ---------------- ELL build: one wave per row, float2 + order-preserving ballot ----------------
__global__ __launch_bounds__(256) void k_ell(const float* __restrict__ A,
                                             int* __restrict__ cols,
                                             int* __restrict__ cnts) {
  int wave = threadIdx.x >> 6, lane = threadIdx.x & 63;
  int row = blockIdx.x * 4 + wave;          // grid 2466 * 4 = 9864 exact
  const float* Ar = A + (size_t)row * N_;   // row stride 9864 B: 8B-aligned -> float2 ok
  int* cp = cols + (size_t)row * ELLW;
  unsigned long long below = (lane == 63) ? 0xFFFFFFFFFFFFFFFFull >> 1
                                          : ((1ull << lane) - 1ull);
  int base = 0;
  for (int i0 = 0; i0 < 20; i0++) {         // 20*128 = 2560 >= 2466
    int j0 = i0 * 128 + lane * 2;
    float2 v = make_float2(0.f, 0.f);
    if (j0 + 1 < N_) v = *(const float2*)&Ar[j0];
    bool nz0 = (j0 < N_) && (v.x != 0.f);
    bool nz1 = (j0 + 1 < N_) && (v.y != 0.f);
    unsigned long long m0 = __ballot(nz0);
    unsigned long long m1 = __ballot(nz1);
    int pre = __popcll(m0 & below) + __popcll(m1 & below);
    int p0 = base + pre;
    int p1 = p0 + (nz0 ? 1 : 0);
    if (nz0 && p0 < ELLW) cp[p0] = j0;
    if (nz1 && p1 < ELLW) cp[p1] = j0 + 1;
    base += __popcll(m0) + __popcll(m1);
  }
  if (lane == 0) cnts[row] = (base > ELLW) ? ELLW : base;
}

// ---------------- split-K fused vertex-align gather + proj GEMM ----------------
__global__ __launch_bounds__(256) void k_align_gemm(
    const float* __restrict__ tr0, const float* __restrict__ tr1,
    const float* __restrict__ tr2, const float* __restrict__ tr3,
    const float* __restrict__ pos, const float* __restrict__ lin_w,
    float* __restrict__ part, int kchunk) {
  __shared__ alignas(16) float Xs[BK][68];    // pad 68: &Xs[kk][cy*8] is 16B-aligned -> ds_read_b128
  __shared__ alignas(16) float Ws[BK][128];
  __shared__ int   sBase[64][4];
  __shared__ float sWgt[64][4];
  int tid = threadIdx.x;
  int m0  = blockIdx.x * 64;
  int s   = blockIdx.y;

  if (tid < 64) {
    int row = m0 + tid;
    const int Sarr[4] = {56, 28, 14, 7};
    const int Carr[4] = {256, 512, 1024, 2048};
    if (row < R_) {
      int b = row / N_;
      float px = pos[row*3+0], py = pos[row*3+1], pz = pos[row*3+2];
      float hh = fminf(fmaxf(248.f*(py/pz)    + 111.5f, 0.f), 223.f);
      float wc = fminf(fmaxf(248.f*(px/(-pz)) + 111.5f, 0.f), 223.f);
      #pragma unroll
      for (int q = 0; q < 4; q++) {
        int S = Sarr[q], C = Carr[q];
        float dv = 224.f / (float)S;
        float x = hh / dv, y = wc / dv;
        int x1 = (int)floorf(x), y1 = (int)floorf(y);
        int x2 = min((int)ceilf(x), S - 1), y2 = min((int)ceilf(y), S - 1);
        sWgt[tid][q]  = (float)((x2 - x1) * (y2 - y1));   // xi==x1,yi==y1 -> only (x1,y1) tap
        sBase[tid][q] = (b * S * S + x1 * S + y1) * C;    // NHWC base; add channel cc
      }
    } else {
      #pragma unroll
      for (int q = 0; q < 4; q++) { sWgt[tid][q] = 0.f; sBase[tid][q] = 0; }
    }
  }
  __syncthreads();

  float acc[8][4];
  #pragma unroll
  for (int r = 0; r < 8; r++)
    #pragma unroll
    for (int c = 0; c < 4; c++) acc[r][c] = 0.f;
  int cx = tid & 31, cy = tid >> 5;

  int kbeg = s * kchunk, kend = kbeg + kchunk;
  for (int k0 = kbeg; k0 < kend; k0 += BK) {
    const float* tr; int off, sI;
    if (k0 < 256)       { tr = tr0; off = 0;    sI = 0; }
    else if (k0 < 768)  { tr = tr1; off = 256;  sI = 1; }
    else if (k0 < 1792) { tr = tr2; off = 768;  sI = 2; }
    else                { tr = tr3; off = 1792; sI = 3; }
    #pragma unroll
    for (int i = 0; i < 8; i++) {
      int e = tid + i * 256;
      int kk = e & 31, m = e >> 5;
      int cc = k0 - off + kk;
      Xs[kk][m] = sWgt[m][sI] * tr[sBase[m][sI] + cc];
    }
    #pragma unroll
    for (int i = 0; i < 4; i++) {
      int slot = tid + i * 256;
      int kk = slot >> 5, c4 = slot & 31;
      *(float4*)&Ws[kk][c4*4] = *(const float4*)&lin_w[(size_t)(k0 + kk)*128 + c4*4];
    }
    __syncthreads();
    #pragma unroll
    for (int kk = 0; kk < BK; kk++) {
      float4 a0 = *(const float4*)&Xs[kk][cy*8];
      float4 a1 = *(const float4*)&Xs[kk][cy*8 + 4];
      float4 bv = *(const float4*)&Ws[kk][cx*4];
      float av[8] = {a0.x, a0.y, a0.z, a0.w, a1.x, a1.y, a1.z, a1.w};
      float bb[4] = {bv.x, bv.y, bv.z, bv.w};
      #pragma unroll
      for (int r = 0; r < 8; r++)
        #pragma unroll
        for (int c = 0; c < 4; c++) acc[r][c] += av[r] * bb[c];
    }
    __syncthreads();
  }

  #pragma unroll
  for (int r = 0; r < 8; r++) {
    int row = m0 + cy*8 + r;
    if (row < R_) {
      float4 v;
      v.x = acc[r][0]; v.y = acc[r][1]; v.z = acc[r][2]; v.w = acc[r][3];
      *(float4*)&part[((size_t)s*R_ + row)*128 + cx*4] = v;
    }
  }
}

// ---------------- reduce partials + bias, build xcat (proj|vf|pos), 2 rows/block ----------------
__global__ __launch_bounds__(256) void k_reduce(
    const float* __restrict__ part, const float* __restrict__ lin_b,
    const float* __restrict__ vf, const float* __restrict__ pos,
    float* __restrict__ xcat, int nsplit) {
  int row = blockIdx.x * 2 + (threadIdx.x >> 7);
  int k = threadIdx.x & 127;
  float acc = lin_b[k];
  for (int s = 0; s < nsplit; s++)
    acc += part[((size_t)s*R_ + row)*128 + k];
  xcat[(size_t)row*264 + k]       = acc;
  xcat[(size_t)row*264 + 128 + k] = vf[(size_t)row*128 + k];
  if (k < 3) xcat[(size_t)row*264 + 256 + k] = pos[(size_t)row*3 + k];
}

// ---------------- tiled GEMM (32x128): out[which] = X @ W[which] (+pb for which==2) ----------------
__global__ __launch_bounds__(256) void k_gemm(
    const float* __restrict__ X, int ldx, int K,
    const float* __restrict__ W0, const float* __restrict__ W1,
    const float* __restrict__ W2, const float* __restrict__ pb,
    float* __restrict__ o0, float* __restrict__ o1, float* __restrict__ o2) {
  __shared__ alignas(16) float Xs[BK][36];    // pad 36: &Xs[kk][cy*4] is 16B-aligned
  __shared__ alignas(16) float Ws[BK][128];
  int tid = threadIdx.x;
  int m0  = blockIdx.x * 32;
  int which = blockIdx.y;
  const float* W = (which == 0) ? W0 : (which == 1) ? W1 : W2;
  float* out     = (which == 0) ? o0 : (which == 1) ? o1 : o2;

  float acc[4][4];
  #pragma unroll
  for (int r = 0; r < 4; r++)
    #pragma unroll
    for (int c = 0; c < 4; c++) acc[r][c] = 0.f;
  int cx = tid & 31, cy = tid >> 5;

  for (int k0 = 0; k0 < K; k0 += BK) {
    {
      int e = tid;
      #pragma unroll
      for (int i = 0; i < 4; i++) {
        int kk = e & 31, m = e >> 5;
        int row = m0 + m, k = k0 + kk;
        Xs[kk][m] = (row < R_ && k < K) ? X[(size_t)row*ldx + k] : 0.f;
        e += 256;
      }
    }
    #pragma unroll
    for (int i = 0; i < 4; i++) {
      int slot = tid + i * 256;
      int kk = slot >> 5, c4 = slot & 31;
      int k = k0 + kk;
      float4 v = make_float4(0.f, 0.f, 0.f, 0.f);
      if (k < K) v = *(const float4*)&W[(size_t)k*128 + c4*4];
      *(float4*)&Ws[kk][c4*4] = v;
    }
    __syncthreads();
    #pragma unroll
    for (int kk = 0; kk < BK; kk++) {
      float4 av4 = *(const float4*)&Xs[kk][cy*4];
      float4 bv  = *(const float4*)&Ws[kk][cx*4];
      float av[4] = {av4.x, av4.y, av4.z, av4.w};
      float bb[4] = {bv.x, bv.y, bv.z, bv.w};
      #pragma unroll
      for (int r = 0; r < 4; r++)
        #pragma unroll
        for (int c = 0; c < 4; c++) acc[r][c] += av[r] * bb[c];
    }
    __syncthreads();
  }

  #pragma unroll
  for (int r = 0; r < 4; r++) {
    int row = m0 + cy*4 + r;
    if (row < R_) {
      int col = cx * 4;
      float4 v;
      v.x = acc[r][0]; v.y = acc[r][1]; v.z = acc[r][2]; v.w = acc[r][3];
      if (which == 2) { v.x += pb[col+0]; v.y += pb[col+1]; v.z += pb[col+2]; v.w += pb[col+3]; }
      *(float4*)&out[(size_t)row*128 + col] = v;
    }
  }
}

// ---------------- SpMM epilogue: out = [skip +] relu(s + A@t), 8 rows/block, float4 ----------------
__global__ __launch_bounds__(256) void k_spmm(
    const float* __restrict__ sb, const float* __restrict__ tb,
    const int* __restrict__ cols, const int* __restrict__ cnts,
    const float* __restrict__ skipb, float* __restrict__ outb) {
  int tid = threadIdx.x;
  int grp = tid >> 5, ln = tid & 31;
  int row = blockIdx.x * 8 + grp;           // grid 1233 * 8 = 9864 exact
  int b = row / N_;
  size_t tbase = (size_t)b * N_;
  const float4* sb4 = (const float4*)sb;
  const float4* tb4 = (const float4*)tb;
  float4 acc = sb4[(size_t)row*32 + ln];
  int cnt = cnts[row];
  const int* cp = cols + (size_t)row * ELLW;
  for (int i = 0; i < cnt; i++) {
    int c = cp[i];
    float4 v = tb4[(tbase + c)*32 + ln];
    acc.x += v.x; acc.y += v.y; acc.z += v.z; acc.w += v.w;
  }
  acc.x = fmaxf(acc.x, 0.f); acc.y = fmaxf(acc.y, 0.f);
  acc.z = fmaxf(acc.z, 0.f); acc.w = fmaxf(acc.w, 0.f);
  if (skipb) {
    float4 sv = ((const float4*)skipb)[(size_t)row*32 + ln];
    acc.x += sv.x; acc.y += sv.y; acc.z += sv.z; acc.w += sv.w;
  }
  ((float4*)outb)[(size_t)row*32 + ln] = acc;
}

// ---------------- final 128->3 GEMV (both weights), one wave per row ----------------
__global__ __launch_bounds__(256) void k_gf_gemv(
    const float* __restrict__ X, const float* __restrict__ w0,
    const float* __restrict__ w1, float* __restrict__ sb, float* __restrict__ tb) {
  int wave = threadIdx.x >> 6, lane = threadIdx.x & 63;
  int row = blockIdx.x * 4 + wave;          // grid 2466
  float xa = X[(size_t)row*128 + lane];
  float xb = X[(size_t)row*128 + 64 + lane];
  #pragma unroll
  for (int c = 0; c < 3; c++) {
    float p = xa * w0[lane*3 + c] + xb * w0[(lane + 64)*3 + c];
    float q = xa * w1[lane*3 + c] + xb * w1[(lane + 64)*3 + c];
    #pragma unroll
    for (int off = 32; off > 0; off >>= 1) {
      p += __shfl_xor(p, off);
      q += __shfl_xor(q, off);
    }
    if (lane == 0) { sb[(size_t)row*128 + c] = p; tb[(size_t)row*128 + c] = q; }
  }
}

// ---------------- final: out = pos + tanh(relu(s + A@t)) ----------------
__global__ __launch_bounds__(256) void k_gf_final(
    const float* __restrict__ sb, const float* __restrict__ tb,
    const int* __restrict__ cols, const int* __restrict__ cnts,
    const float* __restrict__ pos, float* __restrict__ out) {
  int wave = threadIdx.x >> 6, lane = threadIdx.x & 63;
  int row = blockIdx.x * 4 + wave;          // grid 2466
  if (lane >= 3) return;
  int b = row / N_;
  float acc = sb[(size_t)row*128 + lane];
  int cnt = cnts[row];
  const int* cp = cols + (size_t)row * ELLW;
  size_t tbase = (size_t)b * N_;
  for (int i = 0; i < cnt; i++)
    acc += tb[(tbase + cp[i])*128 + lane];
  float v = tanhf(fmaxf(acc, 0.f));
  out[(size_t)row*3 + lane] = pos[(size_t)row*3 + lane] + v;
}

extern "C" void kernel_launch(void* const* d_in, const int* in_sizes, int n_in,
                              void* d_out, int out_size, void* d_ws, size_t ws_size,
                              hipStream_t stream) {
  const float* conv2_3 = (const float*)d_in[0];
  const float* conv3_4 = (const float*)d_in[1];
  const float* conv4_6 = (const float*)d_in[2];
  const float* conv5_3 = (const float*)d_in[3];
  const float* pos     = (const float*)d_in[4];
  const float* vf      = (const float*)d_in[5];
  const float* adj     = (const float*)d_in[6];
  const float* lin_w   = (const float*)d_in[7];
  const float* lin_b   = (const float*)d_in[8];
  const float* r_pw[3]  = {(const float*)d_in[9],  (const float*)d_in[15], (const float*)d_in[21]};
  const float* r_pb[3]  = {(const float*)d_in[10], (const float*)d_in[16], (const float*)d_in[22]};
  const float* r_w00[3] = {(const float*)d_in[11], (const float*)d_in[17], (const float*)d_in[23]};
  const float* r_w01[3] = {(const float*)d_in[12], (const float*)d_in[18], (const float*)d_in[24]};
  const float* r_w10[3] = {(const float*)d_in[13], (const float*)d_in[19], (const float*)d_in[25]};
  const float* r_w11[3] = {(const float*)d_in[14], (const float*)d_in[20], (const float*)d_in[26]};
  const float* gf_w0 = (const float*)d_in[27];
  const float* gf_w1 = (const float*)d_in[28];
  float* out = (float*)d_out;

  // ---- workspace layout (floats) ----
  const size_t TR_TOT = (size_t)4*(256*3136 + 512*784 + 1024*196 + 2048*49);
  const size_t ELL_I  = (size_t)R_ * (ELLW + 1);
  const size_t XCAT_F = (size_t)R_ * 264;

  float* ws  = (float*)d_ws;
  float* tr0 = ws;
  float* tr1 = tr0 + (size_t)4*256*3136;
  float* tr2 = tr1 + (size_t)4*512*784;
  float* tr3 = tr2 + (size_t)4*1024*196;
  int*   ell_cnt  = (int*)(tr3 + (size_t)4*2048*49);
  int*   ell_cols = ell_cnt + R_;
  float* xcat = (float*)(ell_cols + (size_t)R_*ELLW);
  float* buf  = xcat + XCAT_F;          // split-K partials; later sb..xc
  float* sb   = buf;
  float* tb   = sb   + (size_t)R_*128;
  float* skip = tb   + (size_t)R_*128;
  float* hb   = skip + (size_t)R_*128;
  float* xc   = hb   + (size_t)R_*128;

  size_t fixed_f = TR_TOT + ELL_I + XCAT_F;
  size_t need8   = (fixed_f + (size_t)8 * R_ * 128) * sizeof(float);
  int nsplit = (ws_size >= need8) ? 8 : 4;
  int kchunk = 3840 / nsplit;

  // 1) all transposes in one dispatch
  k_transpose_all<<<6144, 256, 0, stream>>>(conv2_3, conv3_4, conv4_6, conv5_3,
                                            tr0, tr1, tr2, tr3);

  // 2) split-K fused align-gather + projection GEMM, then reduce+concat
  k_align_gemm<<<dim3(155, nsplit), 256, 0, stream>>>(tr0, tr1, tr2, tr3, pos, lin_w, buf, kchunk);
  k_reduce<<<4932, 256, 0, stream>>>(buf, lin_b, vf, pos, xcat, nsplit);

  // 3) adjacency (0/1) -> ELL (order-preserving -> bit-exact sums)
  k_ell<<<2466, 256, 0, stream>>>(adj, ell_cols, ell_cnt);

  // 4) three residual graph-conv blocks
  const float* xin = xcat; int ldx = 264, K = 259;
  for (int rb = 0; rb < 3; rb++) {
    k_gemm<<<dim3(309, 3), 256, 0, stream>>>(xin, ldx, K,
        r_w00[rb], r_w01[rb], r_pw[rb], r_pb[rb], sb, tb, skip);
    k_spmm<<<1233, 256, 0, stream>>>(sb, tb, ell_cols, ell_cnt, nullptr, hb);
    k_gemm<<<dim3(309, 2), 256, 0, stream>>>(hb, 128, 128,
        r_w10[rb], r_w11[rb], nullptr, nullptr, sb, tb, nullptr);
    k_spmm<<<1233, 256, 0, stream>>>(sb, tb, ell_cols, ell_cnt, skip, xc);
    xin = xc; ldx = 128; K = 128;
  }

  // 5) final graph conv (128->3) + tanh + residual add
  k_gf_gemv<<<2466, 256, 0, stream>>>(xc, gf_w0, gf_w1, sb, tb);
  k_gf_final<<<2466, 256, 0, stream>>>(sb, tb, ell_cols, ell_cnt, pos, out);
}

// Round 5
// 594.681 us; speedup vs baseline: 3.0232x; 1.0247x over previous
//
#include <hip/hip_runtime.h>
#include <cmath>

#define B_   4
#define N_   2466
#define R_   (B_*N_)     // 9864
#define ELLW 96
#define BK   32

typedef __attribute__((ext_vector_type(8))) short bf16x8;
typedef __attribute__((ext_vector_type(4))) float f32x4;

__device__ __forceinline__ unsigned short bf16_rne(float x) {
  union { float f; unsigned u; } c; c.f = x;
  unsigned r = c.u + 0x7FFFu + ((c.u >> 16) & 1u);
  return (unsigned short)(r >> 16);
}
__device__ __forceinline__ float bf16_back(unsigned short h) {
  union { float f; unsigned u; } c; c.u = ((unsigned)h) << 16;
  return c.f;
}

// ============ fused pre-kernel: transposes + ELL + W hi/lo fragment split ============
// blocks [0,6144): transposes; [6144,8610): ELL; [8610,9090): W split
__global__ __launch_bounds__(256) void k_pre(
    const float* __restrict__ c2, const float* __restrict__ c3,
    const float* __restrict__ c4, const float* __restrict__ c5,
    float* __restrict__ t0, float* __restrict__ t1,
    float* __restrict__ t2, float* __restrict__ t3,
    const float* __restrict__ adj, int* __restrict__ cols, int* __restrict__ cnts,
    const float* __restrict__ lin_w,
    unsigned short* __restrict__ whi, unsigned short* __restrict__ wlo) {
  __shared__ float t[32][33];
  int bid = blockIdx.x;
  if (bid < 6144) {
    const float* in; float* out; int C, P, nx, ny, rem;
    if (bid < 3136)      { in = c2; out = t0; C = 256;  P = 3136; nx = 98; ny = 8;  rem = bid; }
    else if (bid < 4736) { in = c3; out = t1; C = 512;  P = 784;  nx = 25; ny = 16; rem = bid - 3136; }
    else if (bid < 5632) { in = c4; out = t2; C = 1024; P = 196;  nx = 7;  ny = 32; rem = bid - 4736; }
    else                 { in = c5; out = t3; C = 2048; P = 49;   nx = 2;  ny = 64; rem = bid - 5632; }
    int x = rem % nx; int tq = rem / nx; int y = tq % ny; int b = tq / ny;
    int p0 = x * 32, c0 = y * 32;
    int lp = threadIdx.x & 31, lc = threadIdx.x >> 5;
    for (int cc = lc; cc < 32; cc += 8) {
      int c = c0 + cc, p = p0 + lp;
      t[cc][lp] = (c < C && p < P) ? in[((size_t)b*C + c)*P + p] : 0.f;
    }
    __syncthreads();
    for (int pp = lc; pp < 32; pp += 8) {
      int p = p0 + pp, c = c0 + lp;
      if (p < P && c < C) out[((size_t)b*P + p)*C + c] = t[lp][pp];
    }
  } else if (bid < 8610) {
    int wave = threadIdx.x >> 6, lane = threadIdx.x & 63;
    int row = (bid - 6144) * 4 + wave;
    const float* Ar = adj + (size_t)row * N_;
    int* cp = cols + (size_t)row * ELLW;
    unsigned long long below = (lane == 63) ? 0xFFFFFFFFFFFFFFFFull >> 1
                                            : ((1ull << lane) - 1ull);
    int base = 0;
    for (int i0 = 0; i0 < 20; i0++) {
      int j0 = i0 * 128 + lane * 2;
      float2 v = make_float2(0.f, 0.f);
      if (j0 + 1 < N_) v = *(const float2*)&Ar[j0];
      bool nz0 = (j0 < N_) && (v.x != 0.f);
      bool nz1 = (j0 + 1 < N_) && (v.y != 0.f);
      unsigned long long m0 = __ballot(nz0);
      unsigned long long m1 = __ballot(nz1);
      int pre = __popcll(m0 & below) + __popcll(m1 & below);
      int p0 = base + pre;
      int p1 = p0 + (nz0 ? 1 : 0);
      if (nz0 && p0 < ELLW) cp[p0] = j0;
      if (nz1 && p1 < ELLW) cp[p1] = j0 + 1;
      base += __popcll(m0) + __popcll(m1);
    }
    if (lane == 0) cnts[row] = (base > ELLW) ? ELLW : base;
  } else {
    // split lin_w into bf16 hi/lo, arranged in MFMA B-fragment order:
    // e = ((slab*8 + nt)*64 + lane)*8 + j ; k = slab*32 + (lane>>4)*8 + j ; n = nt*16 + (lane&15)
    int b = bid - 8610;                    // 0..479
    int e0 = (b * 256 + threadIdx.x) * 4;
    #pragma unroll
    for (int u = 0; u < 4; u++) {
      int e = e0 + u;                      // < 491520
      int j = e & 7;
      int lane = (e >> 3) & 63;
      int nt = (e >> 9) & 7;
      int slab = e >> 12;
      int k = slab * 32 + ((lane >> 4) << 3) + j;
      int n = nt * 16 + (lane & 15);
      float x = lin_w[(size_t)k * 128 + n];
      unsigned short h = bf16_rne(x);
      whi[e] = h;
      wlo[e] = bf16_rne(x - bf16_back(h));
    }
  }
}

// ============ split-K vertex-align gather + bf16x3 MFMA GEMM ============
// 64x128 tile per block; 4 waves, wave w covers rows [w*16, w*16+16), 8 N-tiles.
__global__ __launch_bounds__(256) void k_align_mfma(
    const float* __restrict__ tr0, const float* __restrict__ tr1,
    const float* __restrict__ tr2, const float* __restrict__ tr3,
    const float* __restrict__ pos,
    const unsigned short* __restrict__ whi, const unsigned short* __restrict__ wlo,
    float* __restrict__ part, int kchunk) {
  int tid  = threadIdx.x;
  int wave = tid >> 6, lane = tid & 63;
  int q    = lane >> 4;                 // k-quad
  int m0   = blockIdx.x * 64;
  int s    = blockIdx.y;
  int mrow = m0 + wave * 16 + (lane & 15);

  // per-lane A-row projection (4x redundant across quads; cheap)
  float wgt[4]; int base[4];
  {
    int rowc = (mrow < R_) ? mrow : 0;
    int b = rowc / N_;
    float px = pos[rowc*3+0], py = pos[rowc*3+1], pz = pos[rowc*3+2];
    float hh = fminf(fmaxf(248.f*(py/pz)    + 111.5f, 0.f), 223.f);
    float wc = fminf(fmaxf(248.f*(px/(-pz)) + 111.5f, 0.f), 223.f);
    const int Sarr[4] = {56, 28, 14, 7};
    const int Carr[4] = {256, 512, 1024, 2048};
    #pragma unroll
    for (int sc = 0; sc < 4; sc++) {
      int S = Sarr[sc], C = Carr[sc];
      float dv = 224.f / (float)S;
      float x = hh / dv, y = wc / dv;
      int x1 = (int)floorf(x), y1 = (int)floorf(y);
      int x2 = min((int)ceilf(x), S - 1), y2 = min((int)ceilf(y), S - 1);
      float w = (float)((x2 - x1) * (y2 - y1));   // xi==x1,yi==y1 -> single tap
      if (mrow >= R_) w = 0.f;
      wgt[sc]  = w;
      base[sc] = (b * S * S + x1 * S + y1) * C;   // NHWC; add channel
    }
  }

  f32x4 acc[8];
  #pragma unroll
  for (int nt = 0; nt < 8; nt++) acc[nt] = (f32x4){0.f, 0.f, 0.f, 0.f};

  const bf16x8* BH = (const bf16x8*)whi;
  const bf16x8* BL = (const bf16x8*)wlo;

  int kbeg = s * kchunk, kend = kbeg + kchunk;
  for (int k0 = kbeg; k0 < kend; k0 += 32) {    // scale bounds (256,768,1792) are x32
    const float* tr; int off, sI;
    if (k0 < 256)       { tr = tr0; off = 0;    sI = 0; }
    else if (k0 < 768)  { tr = tr1; off = 256;  sI = 1; }
    else if (k0 < 1792) { tr = tr2; off = 768;  sI = 2; }
    else                { tr = tr3; off = 1792; sI = 3; }

    // A fragment: A[m=lane&15][k = k0 + q*8 + j], weighted gather, fp32 -> bf16 hi/lo
    const float* src = tr + base[sI] + (k0 - off + q * 8);
    float4 a0 = *(const float4*)src;
    float4 a1 = *(const float4*)(src + 4);
    float wg = wgt[sI];
    float af[8] = {a0.x*wg, a0.y*wg, a0.z*wg, a0.w*wg,
                   a1.x*wg, a1.y*wg, a1.z*wg, a1.w*wg};
    bf16x8 ahi, alo;
    #pragma unroll
    for (int j = 0; j < 8; j++) {
      unsigned short h = bf16_rne(af[j]);
      ahi[j] = (short)h;
      alo[j] = (short)bf16_rne(af[j] - bf16_back(h));
    }

    // B fragments (pre-swizzled, coalesced b128 loads)
    int slab = k0 >> 5;
    bf16x8 Bh[8], Bl[8];
    #pragma unroll
    for (int nt = 0; nt < 8; nt++) {
      size_t fi = (size_t)(slab * 8 + nt) * 64 + lane;
      Bh[nt] = BH[fi];
      Bl[nt] = BL[fi];
    }
    // hi*hi + lo*hi + hi*lo  (lo*lo dropped: ~2^-16 relative)
    #pragma unroll
    for (int nt = 0; nt < 8; nt++)
      acc[nt] = __builtin_amdgcn_mfma_f32_16x16x32_bf16(ahi, Bh[nt], acc[nt], 0, 0, 0);
    #pragma unroll
    for (int nt = 0; nt < 8; nt++)
      acc[nt] = __builtin_amdgcn_mfma_f32_16x16x32_bf16(alo, Bh[nt], acc[nt], 0, 0, 0);
    #pragma unroll
    for (int nt = 0; nt < 8; nt++)
      acc[nt] = __builtin_amdgcn_mfma_f32_16x16x32_bf16(ahi, Bl[nt], acc[nt], 0, 0, 0);
  }

  // C/D layout: col = lane&15, row_in_tile = q*4 + reg  [m89/m91 verified]
  #pragma unroll
  for (int nt = 0; nt < 8; nt++) {
    #pragma unroll
    for (int r = 0; r < 4; r++) {
      int row = m0 + wave * 16 + q * 4 + r;
      if (row < R_)
        part[((size_t)s * R_ + row) * 128 + nt * 16 + (lane & 15)] = acc[nt][r];
    }
  }
}

// ---------------- reduce partials + bias, build xcat (proj|vf|pos), 2 rows/block ----------------
__global__ __launch_bounds__(256) void k_reduce(
    const float* __restrict__ part, const float* __restrict__ lin_b,
    const float* __restrict__ vf, const float* __restrict__ pos,
    float* __restrict__ xcat, int nsplit) {
  int row = blockIdx.x * 2 + (threadIdx.x >> 7);
  int k = threadIdx.x & 127;
  float acc = lin_b[k];
  for (int s = 0; s < nsplit; s++)
    acc += part[((size_t)s*R_ + row)*128 + k];
  xcat[(size_t)row*264 + k]       = acc;
  xcat[(size_t)row*264 + 128 + k] = vf[(size_t)row*128 + k];
  if (k < 3) xcat[(size_t)row*264 + 256 + k] = pos[(size_t)row*3 + k];
}

// ---------------- tiled GEMM (32x128): out[which] = X @ W[which] (+pb for which==2) ----------------
__global__ __launch_bounds__(256) void k_gemm(
    const float* __restrict__ X, int ldx, int K,
    const float* __restrict__ W0, const float* __restrict__ W1,
    const float* __restrict__ W2, const float* __restrict__ pb,
    float* __restrict__ o0, float* __restrict__ o1, float* __restrict__ o2) {
  __shared__ alignas(16) float Xs[BK][36];
  __shared__ alignas(16) float Ws[BK][128];
  int tid = threadIdx.x;
  int m0  = blockIdx.x * 32;
  int which = blockIdx.y;
  const float* W = (which == 0) ? W0 : (which == 1) ? W1 : W2;
  float* out     = (which == 0) ? o0 : (which == 1) ? o1 : o2;

  float acc[4][4];
  #pragma unroll
  for (int r = 0; r < 4; r++)
    #pragma unroll
    for (int c = 0; c < 4; c++) acc[r][c] = 0.f;
  int cx = tid & 31, cy = tid >> 5;

  for (int k0 = 0; k0 < K; k0 += BK) {
    {
      int e = tid;
      #pragma unroll
      for (int i = 0; i < 4; i++) {
        int kk = e & 31, m = e >> 5;
        int row = m0 + m, k = k0 + kk;
        Xs[kk][m] = (row < R_ && k < K) ? X[(size_t)row*ldx + k] : 0.f;
        e += 256;
      }
    }
    #pragma unroll
    for (int i = 0; i < 4; i++) {
      int slot = tid + i * 256;
      int kk = slot >> 5, c4 = slot & 31;
      int k = k0 + kk;
      float4 v = make_float4(0.f, 0.f, 0.f, 0.f);
      if (k < K) v = *(const float4*)&W[(size_t)k*128 + c4*4];
      *(float4*)&Ws[kk][c4*4] = v;
    }
    __syncthreads();
    #pragma unroll
    for (int kk = 0; kk < BK; kk++) {
      float4 av4 = *(const float4*)&Xs[kk][cy*4];
      float4 bv  = *(const float4*)&Ws[kk][cx*4];
      float av[4] = {av4.x, av4.y, av4.z, av4.w};
      float bb[4] = {bv.x, bv.y, bv.z, bv.w};
      #pragma unroll
      for (int r = 0; r < 4; r++)
        #pragma unroll
        for (int c = 0; c < 4; c++) acc[r][c] += av[r] * bb[c];
    }
    __syncthreads();
  }

  #pragma unroll
  for (int r = 0; r < 4; r++) {
    int row = m0 + cy*4 + r;
    if (row < R_) {
      int col = cx * 4;
      float4 v;
      v.x = acc[r][0]; v.y = acc[r][1]; v.z = acc[r][2]; v.w = acc[r][3];
      if (which == 2) { v.x += pb[col+0]; v.y += pb[col+1]; v.z += pb[col+2]; v.w += pb[col+3]; }
      *(float4*)&out[(size_t)row*128 + col] = v;
    }
  }
}

// ---------------- SpMM: out = [skip +] relu(s + A@t); optional fused 128->3 GEMV ----------------
__global__ __launch_bounds__(256) void k_spmm(
    const float* __restrict__ sb, const float* __restrict__ tb,
    const int* __restrict__ cols, const int* __restrict__ cnts,
    const float* __restrict__ skipb, float* __restrict__ outb,
    const float* __restrict__ gw0, const float* __restrict__ gw1,
    float* __restrict__ gsb, float* __restrict__ gtb, int fuse_gf) {
  int tid = threadIdx.x;
  int grp = tid >> 5, ln = tid & 31;
  int row = blockIdx.x * 8 + grp;           // grid 1233 * 8 = 9864 exact
  int b = row / N_;
  size_t tbase = (size_t)b * N_;
  const float4* sb4 = (const float4*)sb;
  const float4* tb4 = (const float4*)tb;
  float4 acc = sb4[(size_t)row*32 + ln];
  int cnt = cnts[row];
  const int* cp = cols + (size_t)row * ELLW;
  for (int i = 0; i < cnt; i++) {
    int c = cp[i];
    float4 v = tb4[(tbase + c)*32 + ln];
    acc.x += v.x; acc.y += v.y; acc.z += v.z; acc.w += v.w;
  }
  acc.x = fmaxf(acc.x, 0.f); acc.y = fmaxf(acc.y, 0.f);
  acc.z = fmaxf(acc.z, 0.f); acc.w = fmaxf(acc.w, 0.f);
  if (skipb) {
    float4 sv = ((const float4*)skipb)[(size_t)row*32 + ln];
    acc.x += sv.x; acc.y += sv.y; acc.z += sv.z; acc.w += sv.w;
  }
  if (!fuse_gf) {
    ((float4*)outb)[(size_t)row*32 + ln] = acc;
    return;
  }
  // fused final gemv: p[c] = sum_j x[j]*gw0[j][c], q likewise; x spread float4/lane
  float av[4] = {acc.x, acc.y, acc.z, acc.w};
  int j0 = ln * 4;
  float p0 = 0.f, p1 = 0.f, p2 = 0.f, q0 = 0.f, q1 = 0.f, q2 = 0.f;
  #pragma unroll
  for (int u = 0; u < 4; u++) {
    int j = j0 + u;
    p0 += av[u] * gw0[j*3+0]; p1 += av[u] * gw0[j*3+1]; p2 += av[u] * gw0[j*3+2];
    q0 += av[u] * gw1[j*3+0]; q1 += av[u] * gw1[j*3+1]; q2 += av[u] * gw1[j*3+2];
  }
  #pragma unroll
  for (int off = 16; off >= 1; off >>= 1) {
    p0 += __shfl_xor(p0, off); p1 += __shfl_xor(p1, off); p2 += __shfl_xor(p2, off);
    q0 += __shfl_xor(q0, off); q1 += __shfl_xor(q1, off); q2 += __shfl_xor(q2, off);
  }
  if (ln == 0) {
    gsb[(size_t)row*128 + 0] = p0; gsb[(size_t)row*128 + 1] = p1; gsb[(size_t)row*128 + 2] = p2;
    gtb[(size_t)row*128 + 0] = q0; gtb[(size_t)row*128 + 1] = q1; gtb[(size_t)row*128 + 2] = q2;
  }
}

// ---------------- final: out = pos + tanh(relu(s + A@t)) ----------------
__global__ __launch_bounds__(256) void k_gf_final(
    const float* __restrict__ sb, const float* __restrict__ tb,
    const int* __restrict__ cols, const int* __restrict__ cnts,
    const float* __restrict__ pos, float* __restrict__ out) {
  int wave = threadIdx.x >> 6, lane = threadIdx.x & 63;
  int row = blockIdx.x * 4 + wave;          // grid 2466
  if (lane >= 3) return;
  int b = row / N_;
  float acc = sb[(size_t)row*128 + lane];
  int cnt = cnts[row];
  const int* cp = cols + (size_t)row * ELLW;
  size_t tbase = (size_t)b * N_;
  for (int i = 0; i < cnt; i++)
    acc += tb[(tbase + cp[i])*128 + lane];
  float v = tanhf(fmaxf(acc, 0.f));
  out[(size_t)row*3 + lane] = pos[(size_t)row*3 + lane] + v;
}

extern "C" void kernel_launch(void* const* d_in, const int* in_sizes, int n_in,
                              void* d_out, int out_size, void* d_ws, size_t ws_size,
                              hipStream_t stream) {
  const float* conv2_3 = (const float*)d_in[0];
  const float* conv3_4 = (const float*)d_in[1];
  const float* conv4_6 = (const float*)d_in[2];
  const float* conv5_3 = (const float*)d_in[3];
  const float* pos     = (const float*)d_in[4];
  const float* vf      = (const float*)d_in[5];
  const float* adj     = (const float*)d_in[6];
  const float* lin_w   = (const float*)d_in[7];
  const float* lin_b   = (const float*)d_in[8];
  const float* r_pw[3]  = {(const float*)d_in[9],  (const float*)d_in[15], (const float*)d_in[21]};
  const float* r_pb[3]  = {(const float*)d_in[10], (const float*)d_in[16], (const float*)d_in[22]};
  const float* r_w00[3] = {(const float*)d_in[11], (const float*)d_in[17], (const float*)d_in[23]};
  const float* r_w01[3] = {(const float*)d_in[12], (const float*)d_in[18], (const float*)d_in[24]};
  const float* r_w10[3] = {(const float*)d_in[13], (const float*)d_in[19], (const float*)d_in[25]};
  const float* r_w11[3] = {(const float*)d_in[14], (const float*)d_in[20], (const float*)d_in[26]};
  const float* gf_w0 = (const float*)d_in[27];
  const float* gf_w1 = (const float*)d_in[28];
  float* out = (float*)d_out;

  // ---- workspace layout (float slots) ----
  const size_t TR_TOT = (size_t)4*(256*3136 + 512*784 + 1024*196 + 2048*49); // 6,021,120
  const size_t ELL_I  = (size_t)R_ * (ELLW + 1);                             //   956,808
  const size_t XCAT_F = (size_t)R_ * 264;                                    // 2,604,096
  const size_t ROWF   = (size_t)R_ * 128;                                    // 1,262,592
  const size_t WSPLIT = 491520;   // float slots reserved for 2x bf16 arrays (2x headroom)

  float* ws  = (float*)d_ws;
  float* tr0 = ws;
  float* tr1 = tr0 + (size_t)4*256*3136;
  float* tr2 = tr1 + (size_t)4*512*784;
  float* tr3 = tr2 + (size_t)4*1024*196;
  int*   ell_cnt  = (int*)(tr3 + (size_t)4*2048*49);
  int*   ell_cols = ell_cnt + R_;
  float* xcat = (float*)(ell_cols + (size_t)R_*ELLW);
  float* buf  = xcat + XCAT_F;          // split-K partials; first 5 slots alias sb..xc
  float* sb   = buf;
  float* tb   = sb   + ROWF;
  float* skip = tb   + ROWF;
  float* hb   = skip + ROWF;
  float* xc   = hb   + ROWF;

  size_t fixed_f = TR_TOT + ELL_I + XCAT_F;
  size_t need8   = (fixed_f + 8 * ROWF + WSPLIT) * sizeof(float);
  int nsplit = (ws_size >= need8) ? 8 : 4;
  int kchunk = 3840 / nsplit;
  size_t bufslots = (size_t)((nsplit > 5) ? nsplit : 5) * ROWF;
  unsigned short* whi = (unsigned short*)(buf + bufslots);
  unsigned short* wlo = whi + 491520;

  // 1) transposes + ELL + W split, one dispatch
  k_pre<<<9090, 256, 0, stream>>>(conv2_3, conv3_4, conv4_6, conv5_3,
                                  tr0, tr1, tr2, tr3,
                                  adj, ell_cols, ell_cnt,
                                  lin_w, whi, wlo);

  // 2) split-K MFMA align-gather GEMM, then reduce+concat
  k_align_mfma<<<dim3(155, nsplit), 256, 0, stream>>>(tr0, tr1, tr2, tr3, pos,
                                                      whi, wlo, buf, kchunk);
  k_reduce<<<4932, 256, 0, stream>>>(buf, lin_b, vf, pos, xcat, nsplit);

  // 3) three residual graph-conv blocks (last spmm fuses the 128->3 gemv)
  const float* xin = xcat; int ldx = 264, K = 259;
  for (int rb = 0; rb < 3; rb++) {
    k_gemm<<<dim3(309, 3), 256, 0, stream>>>(xin, ldx, K,
        r_w00[rb], r_w01[rb], r_pw[rb], r_pb[rb], sb, tb, skip);
    k_spmm<<<1233, 256, 0, stream>>>(sb, tb, ell_cols, ell_cnt, nullptr, hb,
                                     nullptr, nullptr, nullptr, nullptr, 0);
    k_gemm<<<dim3(309, 2), 256, 0, stream>>>(hb, 128, 128,
        r_w10[rb], r_w11[rb], nullptr, nullptr, sb, tb, nullptr);
    if (rb < 2) {
      k_spmm<<<1233, 256, 0, stream>>>(sb, tb, ell_cols, ell_cnt, skip, xc,
                                       nullptr, nullptr, nullptr, nullptr, 0);
    } else {
      k_spmm<<<1233, 256, 0, stream>>>(sb, tb, ell_cols, ell_cnt, skip, nullptr,
                                       gf_w0, gf_w1, hb, xc, 1);   // gsb=hb, gtb=xc
    }
    xin = xc; ldx = 128; K = 128;
  }

  // 4) final: out = pos + tanh(relu(gsb + A@gtb))
  k_gf_final<<<2466, 256, 0, stream>>>(hb, xc, ell_cols, ell_cnt, pos, out);
}